// Round 12
// baseline (367.644 us; speedup 1.0000x reference)
//
#include <hip/hip_runtime.h>
#include <math.h>

typedef __bf16 bf16x8 __attribute__((ext_vector_type(8)));
typedef _Float16 f16x8 __attribute__((ext_vector_type(8)));
typedef float f32x4 __attribute__((ext_vector_type(4)));

__device__ __forceinline__ unsigned short f2bf(float f) {
  unsigned int u = __builtin_bit_cast(unsigned int, f);
  u += 0x7fffu + ((u >> 16) & 1u);
  return (unsigned short)(u >> 16);
}
__device__ __forceinline__ unsigned int pack2bf(float a, float b) {
  return (unsigned int)f2bf(a) | ((unsigned int)f2bf(b) << 16);
}

// ---------- bf16 MFMA GEMM + sigmoid + avgpool2 (unchanged since R3) ----------
#define GK_PADK 40
template <int WFP32, int XFP32>
__global__ __launch_bounds__(256) void gemm_mfma_sig_pool(
    const void* __restrict__ Wv, const float* __restrict__ bias,
    const void* __restrict__ Xv, void* __restrict__ Y,
    int K, int Np, int out_bf16) {
  __shared__ unsigned short Wt[64][GK_PADK];
  __shared__ unsigned short Xt[64][GK_PADK];
  const int tid = threadIdx.x;
  const int i_base = blockIdx.x * 64;
  const int b_base = blockIdx.y * 64;
  const int srow = tid >> 2, sseg = tid & 3;
  const int wv = tid >> 6, lane = tid & 63;
  const int wn = wv & 1, wb = wv >> 1;
  const int L15 = lane & 15, q = lane >> 4;

  f32x4 acc[2][2] = {};
  for (int k0 = 0; k0 < K; k0 += 32) {
    if (WFP32) {
      const float* Wf = (const float*)Wv;
      const float4 a = *(const float4*)&Wf[(size_t)(i_base + srow) * K + k0 + sseg * 8];
      const float4 b = *(const float4*)&Wf[(size_t)(i_base + srow) * K + k0 + sseg * 8 + 4];
      uint4 p = { pack2bf(a.x, a.y), pack2bf(a.z, a.w), pack2bf(b.x, b.y), pack2bf(b.z, b.w) };
      *(uint4*)&Wt[srow][sseg * 8] = p;
    } else {
      *(uint4*)&Wt[srow][sseg * 8] =
          *(const uint4*)&((const unsigned short*)Wv)[(size_t)(i_base + srow) * K + k0 + sseg * 8];
    }
    if (XFP32) {
      const float* Xf = (const float*)Xv;
      const float4 a = *(const float4*)&Xf[(size_t)(b_base + srow) * K + k0 + sseg * 8];
      const float4 b = *(const float4*)&Xf[(size_t)(b_base + srow) * K + k0 + sseg * 8 + 4];
      uint4 p = { pack2bf(a.x, a.y), pack2bf(a.z, a.w), pack2bf(b.x, b.y), pack2bf(b.z, b.w) };
      *(uint4*)&Xt[srow][sseg * 8] = p;
    } else {
      *(uint4*)&Xt[srow][sseg * 8] =
          *(const uint4*)&((const unsigned short*)Xv)[(size_t)(b_base + srow) * K + k0 + sseg * 8];
    }
    __syncthreads();
    bf16x8 a0 = *(const bf16x8*)&Wt[wn * 32 + L15][q * 8];
    bf16x8 a1 = *(const bf16x8*)&Wt[wn * 32 + 16 + L15][q * 8];
    bf16x8 b0 = *(const bf16x8*)&Xt[wb * 32 + L15][q * 8];
    bf16x8 b1 = *(const bf16x8*)&Xt[wb * 32 + 16 + L15][q * 8];
    acc[0][0] = __builtin_amdgcn_mfma_f32_16x16x32_bf16(a0, b0, acc[0][0], 0, 0, 0);
    acc[0][1] = __builtin_amdgcn_mfma_f32_16x16x32_bf16(a0, b1, acc[0][1], 0, 0, 0);
    acc[1][0] = __builtin_amdgcn_mfma_f32_16x16x32_bf16(a1, b0, acc[1][0], 0, 0, 0);
    acc[1][1] = __builtin_amdgcn_mfma_f32_16x16x32_bf16(a1, b1, acc[1][1], 0, 0, 0);
    __syncthreads();
  }

  const int nb0 = i_base + wn * 32;
  const int bc0 = b_base + wb * 32 + L15;
#pragma unroll
  for (int mg = 0; mg < 2; mg++) {
    const int nrow = nb0 + mg * 16 + q * 4;
    const float bi0 = bias[nrow], bi1 = bias[nrow + 1];
    const float bi2 = bias[nrow + 2], bi3 = bias[nrow + 3];
#pragma unroll
    for (int bg = 0; bg < 2; bg++) {
      const int b = bc0 + bg * 16;
      f32x4 A = acc[mg][bg];
      const float a0 = __builtin_amdgcn_rcpf(1.f + __expf(-(A[0] + bi0)));
      const float a1 = __builtin_amdgcn_rcpf(1.f + __expf(-(A[1] + bi1)));
      const float a2 = __builtin_amdgcn_rcpf(1.f + __expf(-(A[2] + bi2)));
      const float a3 = __builtin_amdgcn_rcpf(1.f + __expf(-(A[3] + bi3)));
      const float p0 = 0.5f * (a0 + a1), p1 = 0.5f * (a2 + a3);
      const int pidx = nrow >> 1;  // even
      if (out_bf16) {
        *(unsigned int*)&((unsigned short*)Y)[(size_t)b * Np + pidx] = pack2bf(p0, p1);
      } else {
        *(float2*)&((float*)Y)[(size_t)b * Np + pidx] = make_float2(p0, p1);
      }
    }
  }
}

// ---------- prep: Whh -> fp16, hid-interleaved rows, K padded to 128 ----------
// Perm row 4*hid+gate = Whh[gate*100+hid][0:100]; col 100 = b3[row]; col 101 =
// Wih[row]; cols 102..127 = 0. (Bias/Wih folded into the matmul as extra K.)
__global__ __launch_bounds__(256) void prep_whh(
    const float* __restrict__ Whh, const float* __restrict__ Wih,
    const float* __restrict__ b3, _Float16* __restrict__ P) {
  const int idx = blockIdx.x * 256 + threadIdx.x;  // (row, chunk-of-8)
  if (idx >= 400 * 16) return;
  const int row = idx >> 4, ch = idx & 15;
  const int hid = row >> 2, gate = row & 3;
  const int src = gate * 100 + hid;
  f16x8 v;
#pragma unroll
  for (int j = 0; j < 8; j++) {
    const int k = ch * 8 + j;
    float f = 0.f;
    if (k < 100) f = Whh[(size_t)src * 100 + k];
    else if (k == 100) f = b3[src];
    else if (k == 101) f = Wih[src];
    v[j] = (_Float16)f;
  }
  *(f16x8*)&P[(size_t)row * 128 + ch * 8] = v;
}

// ---------- MFMA LSTM, 1 batch per WG (all 256 CUs) ----------
// Matvec-as-MFMA with replicated-column B: B[k][n] = h[k] for all n, so
// D[m][n] = z_m. Tile t covers perm rows 16t..16t+15 = hids 4t..4t+3 x 4
// gates; C/D layout (row=quad*4+reg, col=c) puts gates i,f,g,o of hid
// (4t+quad) into one lane's f32x4 -> in-lane cell update, no gate exchange.
// Weights = 16 A-fragments/lane, loaded once; MFMA reads A from VGPR OR AGPR
// in place (gfx950 AV classes), so the 64-arch-VGPR cap costs nothing.
// h (+1.0 at k=100, x_t at k=101) lives as fp16[128] in LDS; B-frag = one
// broadcast ds_read_b128 per K-tile. One barrier per step.
#define TSTEPS 256

__global__ __launch_bounds__(512) void lstm_mfma(
    const float* __restrict__ X, const _Float16* __restrict__ P,
    const float* __restrict__ Wout, const float* __restrict__ bout,
    float* __restrict__ out) {
  const int bat = blockIdx.x;
  const int t = threadIdx.x;
  const int w = t >> 6, lane = t & 63;
  const int quad = lane >> 4, c = lane & 15;
  const int TB = (w == 7) ? 21 : w * 3;  // waves 0-6 own 3 tiles, wave 7 owns 4
                                          // (all compute 4; duplicates unwritten)
  __shared__ __align__(16) _Float16 hbuf[2][144];
  __shared__ float xrow[TSTEPS];
  __shared__ float red[128];

  for (int i = t; i < TSTEPS; i += 512) xrow[i] = X[(size_t)bat * TSTEPS + i];
  if (t < 144) { hbuf[0][t] = (_Float16)0.f; hbuf[1][t] = (_Float16)0.f; }
  __syncthreads();
  if (t == 0) {
    hbuf[0][100] = (_Float16)1.f; hbuf[1][100] = (_Float16)1.f;  // bias slot
    hbuf[0][101] = (_Float16)xrow[0];                             // x slot
  }

  // 16 named A-fragments: tile j (rows 16(TB+j)+c), K-tile kt (k = 32kt+8quad)
#define LDA(J, KT) const f16x8 A##J##KT = \
    *(const f16x8*)&P[(size_t)((TB + J) * 16 + c) * 128 + (KT) * 32 + quad * 8];
  LDA(0,0) LDA(0,1) LDA(0,2) LDA(0,3)
  LDA(1,0) LDA(1,1) LDA(1,2) LDA(1,3)
  LDA(2,0) LDA(2,1) LDA(2,2) LDA(2,3)
  LDA(3,0) LDA(3,1) LDA(3,2) LDA(3,3)
#undef LDA

  float c0 = 0.f, c1 = 0.f, c2 = 0.f, c3 = 0.f;
  __syncthreads();

#define SIG(zz) __builtin_amdgcn_rcpf(1.f + __expf(-(zz)))
  for (int step = 0; step < TSTEPS; step++) {
    const int cur = step & 1, nxt = cur ^ 1;
    const _Float16* hc = hbuf[cur];
    const f16x8 B0 = *(const f16x8*)&hc[0 * 32 + quad * 8];
    const f16x8 B1 = *(const f16x8*)&hc[1 * 32 + quad * 8];
    const f16x8 B2 = *(const f16x8*)&hc[2 * 32 + quad * 8];
    const f16x8 B3 = *(const f16x8*)&hc[3 * 32 + quad * 8];

#define TILE(J, CC)                                                          \
    {                                                                        \
      f32x4 z = {0.f, 0.f, 0.f, 0.f};                                        \
      z = __builtin_amdgcn_mfma_f32_16x16x32_f16(A##J##0, B0, z, 0, 0, 0);   \
      z = __builtin_amdgcn_mfma_f32_16x16x32_f16(A##J##1, B1, z, 0, 0, 0);   \
      z = __builtin_amdgcn_mfma_f32_16x16x32_f16(A##J##2, B2, z, 0, 0, 0);   \
      z = __builtin_amdgcn_mfma_f32_16x16x32_f16(A##J##3, B3, z, 0, 0, 0);   \
      const float ai = SIG(z[0]);                                            \
      const float af = SIG(z[1]);                                            \
      const float ag = 2.f * SIG(2.f * z[2]) - 1.f;                          \
      const float ao = SIG(z[3]);                                            \
      CC = fmaf(af, CC, ai * ag);                                            \
      const float th = 2.f * SIG(2.f * CC) - 1.f;                            \
      if ((w == 7 || (J) < 3) && c == 0)                                     \
        hbuf[nxt][4 * (TB + (J)) + quad] = (_Float16)(ao * th);              \
    }
    TILE(0, c0)
    TILE(1, c1)
    TILE(2, c2)
    TILE(3, c3)
#undef TILE
    if (t == 0) hbuf[nxt][101] = (_Float16)xrow[(step + 1 < TSTEPS) ? step + 1 : step];
    __syncthreads();
  }
#undef SIG

  // out[bat] = dot(h_final, Wout) + bout; final h in hbuf[0] (256 even)
  if (t < 128) {
    float a = 0.f;
    if (t < 100) a = (float)hbuf[0][t] * Wout[t];
    red[t] = a;
  }
  __syncthreads();
  if (t == 0) {
    float s = 0.f;
#pragma unroll
    for (int k = 0; k < 128; k++) s += red[k];
    out[bat] = s + bout[0];
  }
}

// ---------- launch ----------
extern "C" void kernel_launch(void* const* d_in, const int* in_sizes, int n_in,
                              void* d_out, int out_size, void* d_ws, size_t ws_size,
                              hipStream_t stream) {
  const float* x    = (const float*)d_in[0];   // (256,1024)
  const float* W1L  = (const float*)d_in[3];   // (1024,1024)
  const float* b1L  = (const float*)d_in[4];
  const float* W2L  = (const float*)d_in[7];   // (512,512)
  const float* b2L  = (const float*)d_in[8];
  const float* Wih3 = (const float*)d_in[15];  // (400,1)
  const float* Whh3 = (const float*)d_in[16];  // (400,100)
  const float* b3   = (const float*)d_in[17];  // (400,)
  const float* Wout = (const float*)d_in[18];  // (1,100)
  const float* bout = (const float*)d_in[19];  // (1,)
  float* out = (float*)d_out;                  // (256,)

  unsigned short* xl1b = (unsigned short*)d_ws;      // 256x512 bf16 (262144 us)
  float* xl2 = (float*)(xl1b + (size_t)256 * 512);   // 256x256 f32  (65536 f)
  _Float16* P = (_Float16*)(xl2 + (size_t)256 * 256);  // 400x128 fp16 (102.4 KB)

  prep_whh<<<25, 256, 0, stream>>>(Whh3, Wih3, b3, P);
  gemm_mfma_sig_pool<1, 1><<<dim3(16, 4), 256, 0, stream>>>(W1L, b1L, x, xl1b, 1024, 512, 1);
  gemm_mfma_sig_pool<1, 0><<<dim3(8, 4), 256, 0, stream>>>(W2L, b2L, xl1b, xl2, 512, 256, 0);
  lstm_mfma<<<256, 512, 0, stream>>>(xl2, P, Wout, bout, out);
}

// Round 14
// 291.206 us; speedup vs baseline: 1.2625x; 1.2625x over previous
//
#include <hip/hip_runtime.h>
#include <math.h>

typedef __bf16 bf16x8 __attribute__((ext_vector_type(8)));
typedef _Float16 f16x8 __attribute__((ext_vector_type(8)));
typedef float f32x4 __attribute__((ext_vector_type(4)));

__device__ __forceinline__ unsigned short f2bf(float f) {
  unsigned int u = __builtin_bit_cast(unsigned int, f);
  u += 0x7fffu + ((u >> 16) & 1u);
  return (unsigned short)(u >> 16);
}
__device__ __forceinline__ unsigned int pack2bf(float a, float b) {
  return (unsigned int)f2bf(a) | ((unsigned int)f2bf(b) << 16);
}

// ---------- bf16 MFMA GEMM + sigmoid + avgpool2 (unchanged since R3) ----------
#define GK_PADK 40
template <int WFP32, int XFP32>
__global__ __launch_bounds__(256) void gemm_mfma_sig_pool(
    const void* __restrict__ Wv, const float* __restrict__ bias,
    const void* __restrict__ Xv, void* __restrict__ Y,
    int K, int Np, int out_bf16) {
  __shared__ unsigned short Wt[64][GK_PADK];
  __shared__ unsigned short Xt[64][GK_PADK];
  const int tid = threadIdx.x;
  const int i_base = blockIdx.x * 64;
  const int b_base = blockIdx.y * 64;
  const int srow = tid >> 2, sseg = tid & 3;
  const int wv = tid >> 6, lane = tid & 63;
  const int wn = wv & 1, wb = wv >> 1;
  const int L15 = lane & 15, q = lane >> 4;

  f32x4 acc[2][2] = {};
  for (int k0 = 0; k0 < K; k0 += 32) {
    if (WFP32) {
      const float* Wf = (const float*)Wv;
      const float4 a = *(const float4*)&Wf[(size_t)(i_base + srow) * K + k0 + sseg * 8];
      const float4 b = *(const float4*)&Wf[(size_t)(i_base + srow) * K + k0 + sseg * 8 + 4];
      uint4 p = { pack2bf(a.x, a.y), pack2bf(a.z, a.w), pack2bf(b.x, b.y), pack2bf(b.z, b.w) };
      *(uint4*)&Wt[srow][sseg * 8] = p;
    } else {
      *(uint4*)&Wt[srow][sseg * 8] =
          *(const uint4*)&((const unsigned short*)Wv)[(size_t)(i_base + srow) * K + k0 + sseg * 8];
    }
    if (XFP32) {
      const float* Xf = (const float*)Xv;
      const float4 a = *(const float4*)&Xf[(size_t)(b_base + srow) * K + k0 + sseg * 8];
      const float4 b = *(const float4*)&Xf[(size_t)(b_base + srow) * K + k0 + sseg * 8 + 4];
      uint4 p = { pack2bf(a.x, a.y), pack2bf(a.z, a.w), pack2bf(b.x, b.y), pack2bf(b.z, b.w) };
      *(uint4*)&Xt[srow][sseg * 8] = p;
    } else {
      *(uint4*)&Xt[srow][sseg * 8] =
          *(const uint4*)&((const unsigned short*)Xv)[(size_t)(b_base + srow) * K + k0 + sseg * 8];
    }
    __syncthreads();
    bf16x8 a0 = *(const bf16x8*)&Wt[wn * 32 + L15][q * 8];
    bf16x8 a1 = *(const bf16x8*)&Wt[wn * 32 + 16 + L15][q * 8];
    bf16x8 b0 = *(const bf16x8*)&Xt[wb * 32 + L15][q * 8];
    bf16x8 b1 = *(const bf16x8*)&Xt[wb * 32 + 16 + L15][q * 8];
    acc[0][0] = __builtin_amdgcn_mfma_f32_16x16x32_bf16(a0, b0, acc[0][0], 0, 0, 0);
    acc[0][1] = __builtin_amdgcn_mfma_f32_16x16x32_bf16(a0, b1, acc[0][1], 0, 0, 0);
    acc[1][0] = __builtin_amdgcn_mfma_f32_16x16x32_bf16(a1, b0, acc[1][0], 0, 0, 0);
    acc[1][1] = __builtin_amdgcn_mfma_f32_16x16x32_bf16(a1, b1, acc[1][1], 0, 0, 0);
    __syncthreads();
  }

  const int nb0 = i_base + wn * 32;
  const int bc0 = b_base + wb * 32 + L15;
#pragma unroll
  for (int mg = 0; mg < 2; mg++) {
    const int nrow = nb0 + mg * 16 + q * 4;
    const float bi0 = bias[nrow], bi1 = bias[nrow + 1];
    const float bi2 = bias[nrow + 2], bi3 = bias[nrow + 3];
#pragma unroll
    for (int bg = 0; bg < 2; bg++) {
      const int b = bc0 + bg * 16;
      f32x4 A = acc[mg][bg];
      const float a0 = __builtin_amdgcn_rcpf(1.f + __expf(-(A[0] + bi0)));
      const float a1 = __builtin_amdgcn_rcpf(1.f + __expf(-(A[1] + bi1)));
      const float a2 = __builtin_amdgcn_rcpf(1.f + __expf(-(A[2] + bi2)));
      const float a3 = __builtin_amdgcn_rcpf(1.f + __expf(-(A[3] + bi3)));
      const float p0 = 0.5f * (a0 + a1), p1 = 0.5f * (a2 + a3);
      const int pidx = nrow >> 1;  // even
      if (out_bf16) {
        *(unsigned int*)&((unsigned short*)Y)[(size_t)b * Np + pidx] = pack2bf(p0, p1);
      } else {
        *(float2*)&((float*)Y)[(size_t)b * Np + pidx] = make_float2(p0, p1);
      }
    }
  }
}

// ---------- prep: Whh -> fp16, hid-interleaved rows, K padded to 128 ----------
// Perm row 4*hid+gate = Whh[gate*100+hid][0:100]; col 100 = b3[row]; col 101 =
// Wih[row]; cols 102..127 = 0. (Bias/Wih folded into the matmul as extra K.)
__global__ __launch_bounds__(256) void prep_whh(
    const float* __restrict__ Whh, const float* __restrict__ Wih,
    const float* __restrict__ b3, _Float16* __restrict__ P) {
  const int idx = blockIdx.x * 256 + threadIdx.x;  // (row, chunk-of-8)
  if (idx >= 400 * 16) return;
  const int row = idx >> 4, ch = idx & 15;
  const int hid = row >> 2, gate = row & 3;
  const int src = gate * 100 + hid;
  f16x8 v;
#pragma unroll
  for (int j = 0; j < 8; j++) {
    const int k = ch * 8 + j;
    float f = 0.f;
    if (k < 100) f = Whh[(size_t)src * 100 + k];
    else if (k == 100) f = b3[src];
    else if (k == 101) f = Wih[src];
    v[j] = (_Float16)f;
  }
  *(f16x8*)&P[(size_t)row * 128 + ch * 8] = v;
}

// ---------- MFMA LSTM, 1 batch per WG, deduped (R14 = R13 + init barrier) ----------
// Matvec-as-MFMA (A = gate-interleaved fp16 weights resident as MFMA
// fragments, consumed in place from AGPRs; B = replicated-column h via one
// broadcast ds_read per K-tile; bias/Wih folded at K=100/101). Tile dedup:
// waves 0-6 do 3 tiles, wave 7 does 4 -> 100 unique MFMA/step. Activation
// dedup: c==0 lanes scatter f32x4 z to zbuf; threads t<100 activate one hid
// each. R13's failure was a RACE: the t==0 writes of the bias/x slots
// (hbuf[*][100]=1.0, [101]=x0) ran concurrently with the t<144 zero-init --
// when the zero landed last, the folded bias column was multiplied by 0
// (absmax 8.8e-3). Fixed with the init __syncthreads() R12 had.
#define TSTEPS 256

__global__ __launch_bounds__(512) void lstm_mfma(
    const float* __restrict__ X, const _Float16* __restrict__ P,
    const float* __restrict__ Wout, const float* __restrict__ bout,
    float* __restrict__ out) {
  const int bat = blockIdx.x;
  const int t = threadIdx.x;
  const int w = t >> 6, lane = t & 63;
  const int quad = lane >> 4, c = lane & 15;
  const int TB = (w == 7) ? 21 : w * 3;  // tile base; wave 7 owns 4 tiles

  __shared__ __align__(16) _Float16 hbuf[2][144];
  __shared__ float xrow[TSTEPS];
  __shared__ __align__(16) float zbuf[400];
  __shared__ float red[128];

  for (int i = t; i < TSTEPS; i += 512) xrow[i] = X[(size_t)bat * TSTEPS + i];
  if (t < 144) { hbuf[0][t] = (_Float16)0.f; hbuf[1][t] = (_Float16)0.f; }
  __syncthreads();  // <-- the barrier R13 dropped: zero-init must land first
  if (t == 0) {
    hbuf[0][100] = (_Float16)1.f; hbuf[1][100] = (_Float16)1.f;   // bias slot
    hbuf[0][101] = (_Float16)xrow[0];                             // x_0 slot
  }

  // 16 A-fragments: tile j (perm rows 16(TB+j)+c), K-tile kt (k = 32kt+8quad)
#define LDA(J, KT) const f16x8 A##J##KT = \
    *(const f16x8*)&P[(size_t)((TB + J) * 16 + c) * 128 + (KT) * 32 + quad * 8];
  LDA(0,0) LDA(0,1) LDA(0,2) LDA(0,3)
  LDA(1,0) LDA(1,1) LDA(1,2) LDA(1,3)
  LDA(2,0) LDA(2,1) LDA(2,2) LDA(2,3)
  LDA(3,0) LDA(3,1) LDA(3,2) LDA(3,3)
#undef LDA

  float cst = 0.f;  // cell state: meaningful on threads t < 100
  __syncthreads();

#define SIG(zz) __builtin_amdgcn_rcpf(1.f + __expf(-(zz)))
  for (int step = 0; step < TSTEPS; step++) {
    const int cur = step & 1, nxt = cur ^ 1;
    const _Float16* hc = hbuf[cur];
    const f16x8 B0 = *(const f16x8*)&hc[0 * 32 + quad * 8];
    const f16x8 B1 = *(const f16x8*)&hc[1 * 32 + quad * 8];
    const f16x8 B2 = *(const f16x8*)&hc[2 * 32 + quad * 8];
    const f16x8 B3 = *(const f16x8*)&hc[3 * 32 + quad * 8];

#define TILE(J)                                                              \
    {                                                                        \
      f32x4 z = {0.f, 0.f, 0.f, 0.f};                                        \
      z = __builtin_amdgcn_mfma_f32_16x16x32_f16(A##J##0, B0, z, 0, 0, 0);   \
      z = __builtin_amdgcn_mfma_f32_16x16x32_f16(A##J##1, B1, z, 0, 0, 0);   \
      z = __builtin_amdgcn_mfma_f32_16x16x32_f16(A##J##2, B2, z, 0, 0, 0);   \
      z = __builtin_amdgcn_mfma_f32_16x16x32_f16(A##J##3, B3, z, 0, 0, 0);   \
      if (c == 0) *(f32x4*)&zbuf[(TB + (J)) * 16 + quad * 4] = z;            \
    }
    TILE(0)
    TILE(1)
    TILE(2)
    if (w == 7) TILE(3)
#undef TILE
    __syncthreads();

    if (t < 100) {  // one hid per thread: rows 4t..4t+3 = gates i,f,g,o
      const float4 zz = *(const float4*)&zbuf[4 * t];
      const float ai = SIG(zz.x);
      const float af = SIG(zz.y);
      const float ag = 2.f * SIG(2.f * zz.z) - 1.f;
      const float ao = SIG(zz.w);
      cst = fmaf(af, cst, ai * ag);
      const float th = 2.f * SIG(2.f * cst) - 1.f;
      hbuf[nxt][t] = (_Float16)(ao * th);
    }
    if (t == 0)
      hbuf[nxt][101] = (_Float16)xrow[(step + 1 < TSTEPS) ? step + 1 : step];
    __syncthreads();
  }
#undef SIG

  // out[bat] = dot(h_final, Wout) + bout; final h in hbuf[0] (256 even)
  if (t < 128) {
    float a = 0.f;
    if (t < 100) a = (float)hbuf[0][t] * Wout[t];
    red[t] = a;
  }
  __syncthreads();
  if (t == 0) {
    float s = 0.f;
#pragma unroll
    for (int k = 0; k < 128; k++) s += red[k];
    out[bat] = s + bout[0];
  }
}

// ---------- launch ----------
extern "C" void kernel_launch(void* const* d_in, const int* in_sizes, int n_in,
                              void* d_out, int out_size, void* d_ws, size_t ws_size,
                              hipStream_t stream) {
  const float* x    = (const float*)d_in[0];   // (256,1024)
  const float* W1L  = (const float*)d_in[3];   // (1024,1024)
  const float* b1L  = (const float*)d_in[4];
  const float* W2L  = (const float*)d_in[7];   // (512,512)
  const float* b2L  = (const float*)d_in[8];
  const float* Wih3 = (const float*)d_in[15];  // (400,1)
  const float* Whh3 = (const float*)d_in[16];  // (400,100)
  const float* b3   = (const float*)d_in[17];  // (400,)
  const float* Wout = (const float*)d_in[18];  // (1,100)
  const float* bout = (const float*)d_in[19];  // (1,)
  float* out = (float*)d_out;                  // (256,)

  unsigned short* xl1b = (unsigned short*)d_ws;        // 256x512 bf16
  float* xl2 = (float*)(xl1b + (size_t)256 * 512);     // 256x256 f32
  _Float16* P = (_Float16*)(xl2 + (size_t)256 * 256);  // 400x128 fp16

  prep_whh<<<25, 256, 0, stream>>>(Whh3, Wih3, b3, P);
  gemm_mfma_sig_pool<1, 1><<<dim3(16, 4), 256, 0, stream>>>(W1L, b1L, x, xl1b, 1024, 512, 1);
  gemm_mfma_sig_pool<1, 0><<<dim3(8, 4), 256, 0, stream>>>(W2L, b2L, xl1b, xl2, 512, 256, 0);
  lstm_mfma<<<256, 512, 0, stream>>>(xl2, P, Wout, bout, out);
}

// Round 15
// 276.086 us; speedup vs baseline: 1.3316x; 1.0548x over previous
//
#include <hip/hip_runtime.h>
#include <math.h>

typedef __bf16 bf16x8 __attribute__((ext_vector_type(8)));
typedef _Float16 f16x8 __attribute__((ext_vector_type(8)));
typedef float f32x4 __attribute__((ext_vector_type(4)));

__device__ __forceinline__ unsigned short f2bf(float f) {
  unsigned int u = __builtin_bit_cast(unsigned int, f);
  u += 0x7fffu + ((u >> 16) & 1u);
  return (unsigned short)(u >> 16);
}
__device__ __forceinline__ unsigned int pack2bf(float a, float b) {
  return (unsigned int)f2bf(a) | ((unsigned int)f2bf(b) << 16);
}

// ---------- bf16 MFMA GEMM + sigmoid + avgpool2 (unchanged since R3) ----------
#define GK_PADK 40
template <int WFP32, int XFP32>
__global__ __launch_bounds__(256) void gemm_mfma_sig_pool(
    const void* __restrict__ Wv, const float* __restrict__ bias,
    const void* __restrict__ Xv, void* __restrict__ Y,
    int K, int Np, int out_bf16) {
  __shared__ unsigned short Wt[64][GK_PADK];
  __shared__ unsigned short Xt[64][GK_PADK];
  const int tid = threadIdx.x;
  const int i_base = blockIdx.x * 64;
  const int b_base = blockIdx.y * 64;
  const int srow = tid >> 2, sseg = tid & 3;
  const int wv = tid >> 6, lane = tid & 63;
  const int wn = wv & 1, wb = wv >> 1;
  const int L15 = lane & 15, q = lane >> 4;

  f32x4 acc[2][2] = {};
  for (int k0 = 0; k0 < K; k0 += 32) {
    if (WFP32) {
      const float* Wf = (const float*)Wv;
      const float4 a = *(const float4*)&Wf[(size_t)(i_base + srow) * K + k0 + sseg * 8];
      const float4 b = *(const float4*)&Wf[(size_t)(i_base + srow) * K + k0 + sseg * 8 + 4];
      uint4 p = { pack2bf(a.x, a.y), pack2bf(a.z, a.w), pack2bf(b.x, b.y), pack2bf(b.z, b.w) };
      *(uint4*)&Wt[srow][sseg * 8] = p;
    } else {
      *(uint4*)&Wt[srow][sseg * 8] =
          *(const uint4*)&((const unsigned short*)Wv)[(size_t)(i_base + srow) * K + k0 + sseg * 8];
    }
    if (XFP32) {
      const float* Xf = (const float*)Xv;
      const float4 a = *(const float4*)&Xf[(size_t)(b_base + srow) * K + k0 + sseg * 8];
      const float4 b = *(const float4*)&Xf[(size_t)(b_base + srow) * K + k0 + sseg * 8 + 4];
      uint4 p = { pack2bf(a.x, a.y), pack2bf(a.z, a.w), pack2bf(b.x, b.y), pack2bf(b.z, b.w) };
      *(uint4*)&Xt[srow][sseg * 8] = p;
    } else {
      *(uint4*)&Xt[srow][sseg * 8] =
          *(const uint4*)&((const unsigned short*)Xv)[(size_t)(b_base + srow) * K + k0 + sseg * 8];
    }
    __syncthreads();
    bf16x8 a0 = *(const bf16x8*)&Wt[wn * 32 + L15][q * 8];
    bf16x8 a1 = *(const bf16x8*)&Wt[wn * 32 + 16 + L15][q * 8];
    bf16x8 b0 = *(const bf16x8*)&Xt[wb * 32 + L15][q * 8];
    bf16x8 b1 = *(const bf16x8*)&Xt[wb * 32 + 16 + L15][q * 8];
    acc[0][0] = __builtin_amdgcn_mfma_f32_16x16x32_bf16(a0, b0, acc[0][0], 0, 0, 0);
    acc[0][1] = __builtin_amdgcn_mfma_f32_16x16x32_bf16(a0, b1, acc[0][1], 0, 0, 0);
    acc[1][0] = __builtin_amdgcn_mfma_f32_16x16x32_bf16(a1, b0, acc[1][0], 0, 0, 0);
    acc[1][1] = __builtin_amdgcn_mfma_f32_16x16x32_bf16(a1, b1, acc[1][1], 0, 0, 0);
    __syncthreads();
  }

  const int nb0 = i_base + wn * 32;
  const int bc0 = b_base + wb * 32 + L15;
#pragma unroll
  for (int mg = 0; mg < 2; mg++) {
    const int nrow = nb0 + mg * 16 + q * 4;
    const float bi0 = bias[nrow], bi1 = bias[nrow + 1];
    const float bi2 = bias[nrow + 2], bi3 = bias[nrow + 3];
#pragma unroll
    for (int bg = 0; bg < 2; bg++) {
      const int b = bc0 + bg * 16;
      f32x4 A = acc[mg][bg];
      const float a0 = __builtin_amdgcn_rcpf(1.f + __expf(-(A[0] + bi0)));
      const float a1 = __builtin_amdgcn_rcpf(1.f + __expf(-(A[1] + bi1)));
      const float a2 = __builtin_amdgcn_rcpf(1.f + __expf(-(A[2] + bi2)));
      const float a3 = __builtin_amdgcn_rcpf(1.f + __expf(-(A[3] + bi3)));
      const float p0 = 0.5f * (a0 + a1), p1 = 0.5f * (a2 + a3);
      const int pidx = nrow >> 1;  // even
      if (out_bf16) {
        *(unsigned int*)&((unsigned short*)Y)[(size_t)b * Np + pidx] = pack2bf(p0, p1);
      } else {
        *(float2*)&((float*)Y)[(size_t)b * Np + pidx] = make_float2(p0, p1);
      }
    }
  }
}

// ---------- prep: Whh -> fp16, hid-interleaved rows, K padded to 128 ----------
// Perm row 4*hid+gate = Whh[gate*100+hid][0:100]; col 100 = b3[row]; cols
// 101..127 = 0. (x*Wih is applied in VALU at activation time now.)
__global__ __launch_bounds__(256) void prep_whh(
    const float* __restrict__ Whh, const float* __restrict__ b3,
    _Float16* __restrict__ P) {
  const int idx = blockIdx.x * 256 + threadIdx.x;  // (row, chunk-of-8)
  if (idx >= 400 * 16) return;
  const int row = idx >> 4, ch = idx & 15;
  const int hid = row >> 2, gate = row & 3;
  const int src = gate * 100 + hid;
  f16x8 v;
#pragma unroll
  for (int j = 0; j < 8; j++) {
    const int k = ch * 8 + j;
    float f = 0.f;
    if (k < 100) f = Whh[(size_t)src * 100 + k];
    else if (k == 100) f = b3[src];
    v[j] = (_Float16)f;
  }
  *(f16x8*)&P[(size_t)row * 128 + ch * 8] = v;
}

// ---------- MFMA LSTM, one barrier per step (R15) ----------
// R14 was latency-bound (MfmaUtil 26%, VALUBusy 14%, step 1520 cyc vs ~400
// of work): two barriers + two zbuf LDS round-trips per step. Exploit: the
// 16x16 C/D layout replicates each hid's gate-quad across ALL 16 columns,
// so lane c==J already holds tile TB+J's z in registers -> activate in-lane
// (one hid per lane, shortest chain), write fp16 h directly, ONE barrier.
// Split K-accumulators (two 2-chains + add) halve MFMA dep latency. x*Wih
// folded in VALU (per-lane float4 of Wih rows); bias stays at K=100 vs the
// constant-1.0 h slot. Weights remain resident MFMA A-fragments in AGPRs.
#define TSTEPS 256

__global__ __launch_bounds__(512) void lstm_mfma(
    const float* __restrict__ X, const _Float16* __restrict__ P,
    const float* __restrict__ Wih, const float* __restrict__ Wout,
    const float* __restrict__ bout, float* __restrict__ out) {
  const int bat = blockIdx.x;
  const int t = threadIdx.x;
  const int w = t >> 6, lane = t & 63;
  const int quad = lane >> 4, c = lane & 15;
  const int TB = (w == 7) ? 21 : w * 3;   // tile base
  const int NT = (w == 7) ? 4 : 3;        // tiles this wave owns

  __shared__ __align__(16) _Float16 hbuf[2][128];
  __shared__ float xrow[TSTEPS];
  __shared__ float red[128];

  for (int i = t; i < TSTEPS; i += 512) xrow[i] = X[(size_t)bat * TSTEPS + i];
  if (t < 128) { hbuf[0][t] = (_Float16)0.f; hbuf[1][t] = (_Float16)0.f; }
  __syncthreads();
  if (t < 2) hbuf[t][100] = (_Float16)1.f;  // constant bias slot (both buffers)

  // 16 A-fragments: tile j (perm rows 16(TB+j)+c), K-tile kt (k = 32kt+8quad)
#define LDA(J, KT) const f16x8 A##J##KT = \
    *(const f16x8*)&P[(size_t)((TB + J) * 16 + c) * 128 + (KT) * 32 + quad * 8];
  LDA(0,0) LDA(0,1) LDA(0,2) LDA(0,3)
  LDA(1,0) LDA(1,1) LDA(1,2) LDA(1,3)
  LDA(2,0) LDA(2,1) LDA(2,2) LDA(2,3)
  LDA(3,0) LDA(3,1) LDA(3,2) LDA(3,3)
#undef LDA

  // activation assignment: lane c==J handles hid 4*(TB+J)+quad
  const bool act = (c < NT);
  const int myhid = 4 * (TB + (act ? c : 0)) + quad;  // < 100 always
  const float u_i = Wih[0 * 100 + myhid];
  const float u_f = Wih[1 * 100 + myhid];
  const float u_g = Wih[2 * 100 + myhid];
  const float u_o = Wih[3 * 100 + myhid];
  float cst = 0.f;
  __syncthreads();

#define SIG(zz) __builtin_amdgcn_rcpf(1.f + __expf(-(zz)))
  for (int step = 0; step < TSTEPS; step++) {
    const int cur = step & 1, nxt = cur ^ 1;
    const _Float16* hc = hbuf[cur];
    const f16x8 B0 = *(const f16x8*)&hc[0 * 32 + quad * 8];
    const f16x8 B1 = *(const f16x8*)&hc[1 * 32 + quad * 8];
    const f16x8 B2 = *(const f16x8*)&hc[2 * 32 + quad * 8];
    const f16x8 B3 = *(const f16x8*)&hc[3 * 32 + quad * 8];

    f32x4 z0, z1, z2, z3 = {0.f, 0.f, 0.f, 0.f};
#define TILE(J, ZD)                                                          \
    {                                                                        \
      f32x4 za = {0.f, 0.f, 0.f, 0.f}, zb = za;                              \
      za = __builtin_amdgcn_mfma_f32_16x16x32_f16(A##J##0, B0, za, 0, 0, 0); \
      zb = __builtin_amdgcn_mfma_f32_16x16x32_f16(A##J##2, B2, zb, 0, 0, 0); \
      za = __builtin_amdgcn_mfma_f32_16x16x32_f16(A##J##1, B1, za, 0, 0, 0); \
      zb = __builtin_amdgcn_mfma_f32_16x16x32_f16(A##J##3, B3, zb, 0, 0, 0); \
      ZD = za + zb;                                                          \
    }
    TILE(0, z0)
    TILE(1, z1)
    TILE(2, z2)
    if (w == 7) TILE(3, z3)
#undef TILE

    // in-lane activation: lane c==J owns tile TB+J (z replicated over cols)
    const f32x4 zz = (c == 0) ? z0 : (c == 1) ? z1 : (c == 2) ? z2 : z3;
    if (act) {
      const float xt = xrow[step];
      const float ai = SIG(fmaf(u_i, xt, zz[0]));
      const float af = SIG(fmaf(u_f, xt, zz[1]));
      const float ag = 2.f * SIG(2.f * fmaf(u_g, xt, zz[2])) - 1.f;
      const float ao = SIG(fmaf(u_o, xt, zz[3]));
      cst = fmaf(af, cst, ai * ag);
      const float th = 2.f * SIG(2.f * cst) - 1.f;
      hbuf[nxt][myhid] = (_Float16)(ao * th);
    }
    __syncthreads();
  }
#undef SIG

  // out[bat] = dot(h_final, Wout) + bout; final h in hbuf[0] (256 even)
  if (t < 128) {
    float a = 0.f;
    if (t < 100) a = (float)hbuf[0][t] * Wout[t];
    red[t] = a;
  }
  __syncthreads();
  if (t == 0) {
    float s = 0.f;
#pragma unroll
    for (int k = 0; k < 128; k++) s += red[k];
    out[bat] = s + bout[0];
  }
}

// ---------- launch ----------
extern "C" void kernel_launch(void* const* d_in, const int* in_sizes, int n_in,
                              void* d_out, int out_size, void* d_ws, size_t ws_size,
                              hipStream_t stream) {
  const float* x    = (const float*)d_in[0];   // (256,1024)
  const float* W1L  = (const float*)d_in[3];   // (1024,1024)
  const float* b1L  = (const float*)d_in[4];
  const float* W2L  = (const float*)d_in[7];   // (512,512)
  const float* b2L  = (const float*)d_in[8];
  const float* Wih3 = (const float*)d_in[15];  // (400,1)
  const float* Whh3 = (const float*)d_in[16];  // (400,100)
  const float* b3   = (const float*)d_in[17];  // (400,)
  const float* Wout = (const float*)d_in[18];  // (1,100)
  const float* bout = (const float*)d_in[19];  // (1,)
  float* out = (float*)d_out;                  // (256,)

  unsigned short* xl1b = (unsigned short*)d_ws;        // 256x512 bf16
  float* xl2 = (float*)(xl1b + (size_t)256 * 512);     // 256x256 f32
  _Float16* P = (_Float16*)(xl2 + (size_t)256 * 256);  // 400x128 fp16

  prep_whh<<<25, 256, 0, stream>>>(Whh3, b3, P);
  gemm_mfma_sig_pool<1, 1><<<dim3(16, 4), 256, 0, stream>>>(W1L, b1L, x, xl1b, 1024, 512, 1);
  gemm_mfma_sig_pool<1, 0><<<dim3(8, 4), 256, 0, stream>>>(W2L, b2L, xl1b, xl2, 512, 256, 0);
  lstm_mfma<<<256, 512, 0, stream>>>(xl2, P, Wih3, Wout, bout, out);
}

// Round 16
// 264.631 us; speedup vs baseline: 1.3893x; 1.0433x over previous
//
#include <hip/hip_runtime.h>
#include <math.h>

typedef __bf16 bf16x8 __attribute__((ext_vector_type(8)));
typedef _Float16 f16x8 __attribute__((ext_vector_type(8)));
typedef _Float16 f16x4 __attribute__((ext_vector_type(4)));
typedef float f32x4 __attribute__((ext_vector_type(4)));

__device__ __forceinline__ unsigned short f2bf(float f) {
  unsigned int u = __builtin_bit_cast(unsigned int, f);
  u += 0x7fffu + ((u >> 16) & 1u);
  return (unsigned short)(u >> 16);
}
__device__ __forceinline__ unsigned int pack2bf(float a, float b) {
  return (unsigned int)f2bf(a) | ((unsigned int)f2bf(b) << 16);
}

// ---------- bf16 MFMA GEMM + sigmoid + avgpool2 (unchanged since R3) ----------
#define GK_PADK 40
template <int WFP32, int XFP32>
__global__ __launch_bounds__(256) void gemm_mfma_sig_pool(
    const void* __restrict__ Wv, const float* __restrict__ bias,
    const void* __restrict__ Xv, void* __restrict__ Y,
    int K, int Np, int out_bf16) {
  __shared__ unsigned short Wt[64][GK_PADK];
  __shared__ unsigned short Xt[64][GK_PADK];
  const int tid = threadIdx.x;
  const int i_base = blockIdx.x * 64;
  const int b_base = blockIdx.y * 64;
  const int srow = tid >> 2, sseg = tid & 3;
  const int wv = tid >> 6, lane = tid & 63;
  const int wn = wv & 1, wb = wv >> 1;
  const int L15 = lane & 15, q = lane >> 4;

  f32x4 acc[2][2] = {};
  for (int k0 = 0; k0 < K; k0 += 32) {
    if (WFP32) {
      const float* Wf = (const float*)Wv;
      const float4 a = *(const float4*)&Wf[(size_t)(i_base + srow) * K + k0 + sseg * 8];
      const float4 b = *(const float4*)&Wf[(size_t)(i_base + srow) * K + k0 + sseg * 8 + 4];
      uint4 p = { pack2bf(a.x, a.y), pack2bf(a.z, a.w), pack2bf(b.x, b.y), pack2bf(b.z, b.w) };
      *(uint4*)&Wt[srow][sseg * 8] = p;
    } else {
      *(uint4*)&Wt[srow][sseg * 8] =
          *(const uint4*)&((const unsigned short*)Wv)[(size_t)(i_base + srow) * K + k0 + sseg * 8];
    }
    if (XFP32) {
      const float* Xf = (const float*)Xv;
      const float4 a = *(const float4*)&Xf[(size_t)(b_base + srow) * K + k0 + sseg * 8];
      const float4 b = *(const float4*)&Xf[(size_t)(b_base + srow) * K + k0 + sseg * 8 + 4];
      uint4 p = { pack2bf(a.x, a.y), pack2bf(a.z, a.w), pack2bf(b.x, b.y), pack2bf(b.z, b.w) };
      *(uint4*)&Xt[srow][sseg * 8] = p;
    } else {
      *(uint4*)&Xt[srow][sseg * 8] =
          *(const uint4*)&((const unsigned short*)Xv)[(size_t)(b_base + srow) * K + k0 + sseg * 8];
    }
    __syncthreads();
    bf16x8 a0 = *(const bf16x8*)&Wt[wn * 32 + L15][q * 8];
    bf16x8 a1 = *(const bf16x8*)&Wt[wn * 32 + 16 + L15][q * 8];
    bf16x8 b0 = *(const bf16x8*)&Xt[wb * 32 + L15][q * 8];
    bf16x8 b1 = *(const bf16x8*)&Xt[wb * 32 + 16 + L15][q * 8];
    acc[0][0] = __builtin_amdgcn_mfma_f32_16x16x32_bf16(a0, b0, acc[0][0], 0, 0, 0);
    acc[0][1] = __builtin_amdgcn_mfma_f32_16x16x32_bf16(a0, b1, acc[0][1], 0, 0, 0);
    acc[1][0] = __builtin_amdgcn_mfma_f32_16x16x32_bf16(a1, b0, acc[1][0], 0, 0, 0);
    acc[1][1] = __builtin_amdgcn_mfma_f32_16x16x32_bf16(a1, b1, acc[1][1], 0, 0, 0);
    __syncthreads();
  }

  const int nb0 = i_base + wn * 32;
  const int bc0 = b_base + wb * 32 + L15;
#pragma unroll
  for (int mg = 0; mg < 2; mg++) {
    const int nrow = nb0 + mg * 16 + q * 4;
    const float bi0 = bias[nrow], bi1 = bias[nrow + 1];
    const float bi2 = bias[nrow + 2], bi3 = bias[nrow + 3];
#pragma unroll
    for (int bg = 0; bg < 2; bg++) {
      const int b = bc0 + bg * 16;
      f32x4 A = acc[mg][bg];
      const float a0 = __builtin_amdgcn_rcpf(1.f + __expf(-(A[0] + bi0)));
      const float a1 = __builtin_amdgcn_rcpf(1.f + __expf(-(A[1] + bi1)));
      const float a2 = __builtin_amdgcn_rcpf(1.f + __expf(-(A[2] + bi2)));
      const float a3 = __builtin_amdgcn_rcpf(1.f + __expf(-(A[3] + bi3)));
      const float p0 = 0.5f * (a0 + a1), p1 = 0.5f * (a2 + a3);
      const int pidx = nrow >> 1;  // even
      if (out_bf16) {
        *(unsigned int*)&((unsigned short*)Y)[(size_t)b * Np + pidx] = pack2bf(p0, p1);
      } else {
        *(float2*)&((float*)Y)[(size_t)b * Np + pidx] = make_float2(p0, p1);
      }
    }
  }
}

// ---------- prep: Whh -> fp16, hid-interleaved rows, K-stride 128 ----------
// Perm row 4*hid+gate = Whh[gate*100+hid][0:100]. Only k<96 is consumed by
// MFMA now (k 96..99 + bias + Wih*x handled in fp32 VALU tail).
__global__ __launch_bounds__(256) void prep_whh(
    const float* __restrict__ Whh, const float* __restrict__ b3,
    _Float16* __restrict__ P) {
  const int idx = blockIdx.x * 256 + threadIdx.x;  // (row, chunk-of-8)
  if (idx >= 400 * 16) return;
  const int row = idx >> 4, ch = idx & 15;
  const int hid = row >> 2, gate = row & 3;
  const int src = gate * 100 + hid;
  f16x8 v;
#pragma unroll
  for (int j = 0; j < 8; j++) {
    const int k = ch * 8 + j;
    float f = 0.f;
    if (k < 100) f = Whh[(size_t)src * 100 + k];
    v[j] = (_Float16)f;
  }
  *(f16x8*)&P[(size_t)row * 128 + ch * 8] = v;
}

// ---------- MFMA LSTM (R16): quad-split activation, K-trim, unroll x2 ----------
// R15 diagnosis: step latency-bound (removing a barrier+LDS roundtrip R14->R15
// changed nothing; VALUBusy tripled with flat time). Cuts here: (1) lane
// (quad,c) handles gate c&3 of tile c>>2 via unified m*sig(k*z)+d (trans/wave
// 10->4) with 3 DPP quad-broadcasts to gather gates; cst replicated per DPP
// quad; (2) K-tiles 4->3, k in [96,100)+bias+Wih*x as a 6-FMA fp32 tail;
// (3) step loop unrolled x2 so LDS addresses are loop-invariant;
// (4) launch_bounds(512,2): min-waves matches actual occupancy -> 256-VGPR
// budget, no accvgpr shuttling of B/z/temps (VGPR_Count is the diagnostic).
#define TSTEPS 256

__device__ __forceinline__ float qb0(float x) {
  return __builtin_bit_cast(float, __builtin_amdgcn_mov_dpp(__builtin_bit_cast(int, x), 0x00, 0xf, 0xf, true));
}
__device__ __forceinline__ float qb1(float x) {
  return __builtin_bit_cast(float, __builtin_amdgcn_mov_dpp(__builtin_bit_cast(int, x), 0x55, 0xf, 0xf, true));
}
__device__ __forceinline__ float qb2(float x) {
  return __builtin_bit_cast(float, __builtin_amdgcn_mov_dpp(__builtin_bit_cast(int, x), 0xAA, 0xf, 0xf, true));
}
__device__ __forceinline__ float qb3(float x) {
  return __builtin_bit_cast(float, __builtin_amdgcn_mov_dpp(__builtin_bit_cast(int, x), 0xFF, 0xf, 0xf, true));
}

__global__ __launch_bounds__(512, 2) void lstm_mfma(
    const float* __restrict__ X, const _Float16* __restrict__ P,
    const float* __restrict__ Whh, const float* __restrict__ Wih,
    const float* __restrict__ b3, const float* __restrict__ Wout,
    const float* __restrict__ bout, float* __restrict__ out) {
  const int bat = blockIdx.x;
  const int t = threadIdx.x;
  const int w = t >> 6, lane = t & 63;
  const int quad = lane >> 4, c = lane & 15;
  const int TB = (w == 7) ? 21 : w * 3;   // tile base
  const int NT = (w == 7) ? 4 : 3;        // tiles this wave activates

  __shared__ __align__(16) _Float16 hbuf[2][128];
  __shared__ float xrow[TSTEPS];
  __shared__ float red[128];

  for (int i = t; i < TSTEPS; i += 512) xrow[i] = X[(size_t)bat * TSTEPS + i];
  if (t < 128) { hbuf[0][t] = (_Float16)0.f; hbuf[1][t] = (_Float16)0.f; }

  // 12 A-fragments (tiles TB..TB+3 all valid rows <= 24; tile 3 used only by w==7)
#define LDA(J, KT) const f16x8 A##J##KT = \
    *(const f16x8*)&P[(size_t)((TB + J) * 16 + c) * 128 + (KT) * 32 + quad * 8];
  LDA(0,0) LDA(0,1) LDA(0,2)
  LDA(1,0) LDA(1,1) LDA(1,2)
  LDA(2,0) LDA(2,1) LDA(2,2)
  LDA(3,0) LDA(3,1) LDA(3,2)
#undef LDA

  // activation role: lane handles gate g of hid 4*(TB+J)+quad
  const bool act = (c < 4 * NT);
  const int J = c >> 2, g = c & 3;
  const int myhid = 4 * (TB + (act ? J : 0)) + quad;  // < 100
  const int grow = g * 100 + myhid;                   // row in original gate layout
  const float u_ = Wih[grow];
  const float bz = b3[grow];
  const float4 wt = *(const float4*)&Whh[(size_t)grow * 100 + 96];  // k tail 96..99
  const float kk = (g == 2) ? 2.f : 1.f;   // g-gate is tanh = 2*sig(2z)-1
  const float mm = (g == 2) ? 2.f : 1.f;
  const float dd = (g == 2) ? -1.f : 0.f;
  float cst = 0.f;
  __syncthreads();

#define SIG(zz) __builtin_amdgcn_rcpf(1.f + __expf(-(zz)))
#define STEPB(HC, HN, XT)                                                      \
  {                                                                            \
    const _Float16* hc = (HC);                                                 \
    const f16x8 B0 = *(const f16x8*)&hc[0 * 32 + quad * 8];                    \
    const f16x8 B1 = *(const f16x8*)&hc[1 * 32 + quad * 8];                    \
    const f16x8 B2 = *(const f16x8*)&hc[2 * 32 + quad * 8];                    \
    f32x4 z0 = {0.f,0.f,0.f,0.f}, z1 = z0, z2 = z0, z3 = z0;                   \
    { f32x4 za = z0, zb = z0;                                                  \
      za = __builtin_amdgcn_mfma_f32_16x16x32_f16(A00, B0, za, 0, 0, 0);       \
      zb = __builtin_amdgcn_mfma_f32_16x16x32_f16(A01, B1, zb, 0, 0, 0);       \
      za = __builtin_amdgcn_mfma_f32_16x16x32_f16(A02, B2, za, 0, 0, 0);       \
      z0 = za + zb; }                                                          \
    { f32x4 za = {0.f,0.f,0.f,0.f}, zb = za;                                   \
      za = __builtin_amdgcn_mfma_f32_16x16x32_f16(A10, B0, za, 0, 0, 0);       \
      zb = __builtin_amdgcn_mfma_f32_16x16x32_f16(A11, B1, zb, 0, 0, 0);       \
      za = __builtin_amdgcn_mfma_f32_16x16x32_f16(A12, B2, za, 0, 0, 0);       \
      z1 = za + zb; }                                                          \
    { f32x4 za = {0.f,0.f,0.f,0.f}, zb = za;                                   \
      za = __builtin_amdgcn_mfma_f32_16x16x32_f16(A20, B0, za, 0, 0, 0);       \
      zb = __builtin_amdgcn_mfma_f32_16x16x32_f16(A21, B1, zb, 0, 0, 0);       \
      za = __builtin_amdgcn_mfma_f32_16x16x32_f16(A22, B2, za, 0, 0, 0);       \
      z2 = za + zb; }                                                          \
    if (w == 7) {                                                              \
      f32x4 za = {0.f,0.f,0.f,0.f}, zb = za;                                   \
      za = __builtin_amdgcn_mfma_f32_16x16x32_f16(A30, B0, za, 0, 0, 0);       \
      zb = __builtin_amdgcn_mfma_f32_16x16x32_f16(A31, B1, zb, 0, 0, 0);       \
      za = __builtin_amdgcn_mfma_f32_16x16x32_f16(A32, B2, za, 0, 0, 0);       \
      z3 = za + zb; }                                                          \
    if (act) {                                                                 \
      const f32x4 zt = (J == 0) ? z0 : (J == 1) ? z1 : (J == 2) ? z2 : z3;     \
      float zs = (g == 0) ? zt[0] : (g == 1) ? zt[1] : (g == 2) ? zt[2] : zt[3];\
      const f16x4 ht = *(const f16x4*)&hc[96];                                 \
      zs = fmaf(wt.x, (float)ht[0], zs);                                       \
      zs = fmaf(wt.y, (float)ht[1], zs);                                       \
      zs = fmaf(wt.z, (float)ht[2], zs);                                       \
      zs = fmaf(wt.w, (float)ht[3], zs);                                       \
      zs = fmaf(u_, (XT), zs + bz);                                            \
      const float a = mm * SIG(kk * zs) + dd;                                  \
      const float ai = qb0(a), af = qb1(a), ag = qb2(a), ao = qb3(a);          \
      cst = fmaf(af, cst, ai * ag);                                            \
      const float th = 2.f * SIG(2.f * cst) - 1.f;                             \
      if (g == 0) (HN)[myhid] = (_Float16)(ao * th);                           \
    }                                                                          \
    __syncthreads();                                                           \
  }

  for (int step = 0; step < TSTEPS; step += 2) {
    STEPB(hbuf[0], hbuf[1], xrow[step]);
    STEPB(hbuf[1], hbuf[0], xrow[step + 1]);
  }
#undef STEPB
#undef SIG

  // out[bat] = dot(h_final, Wout) + bout; final h in hbuf[0]
  if (t < 128) {
    float a = 0.f;
    if (t < 100) a = (float)hbuf[0][t] * Wout[t];
    red[t] = a;
  }
  __syncthreads();
  if (t == 0) {
    float s = 0.f;
#pragma unroll
    for (int k = 0; k < 128; k++) s += red[k];
    out[bat] = s + bout[0];
  }
}

// ---------- launch ----------
extern "C" void kernel_launch(void* const* d_in, const int* in_sizes, int n_in,
                              void* d_out, int out_size, void* d_ws, size_t ws_size,
                              hipStream_t stream) {
  const float* x    = (const float*)d_in[0];   // (256,1024)
  const float* W1L  = (const float*)d_in[3];   // (1024,1024)
  const float* b1L  = (const float*)d_in[4];
  const float* W2L  = (const float*)d_in[7];   // (512,512)
  const float* b2L  = (const float*)d_in[8];
  const float* Wih3 = (const float*)d_in[15];  // (400,1)
  const float* Whh3 = (const float*)d_in[16];  // (400,100)
  const float* b3   = (const float*)d_in[17];  // (400,)
  const float* Wout = (const float*)d_in[18];  // (1,100)
  const float* bout = (const float*)d_in[19];  // (1,)
  float* out = (float*)d_out;                  // (256,)

  unsigned short* xl1b = (unsigned short*)d_ws;        // 256x512 bf16
  float* xl2 = (float*)(xl1b + (size_t)256 * 512);     // 256x256 f32
  _Float16* P = (_Float16*)(xl2 + (size_t)256 * 256);  // 400x128 fp16

  prep_whh<<<25, 256, 0, stream>>>(Whh3, b3, P);
  gemm_mfma_sig_pool<1, 1><<<dim3(16, 4), 256, 0, stream>>>(W1L, b1L, x, xl1b, 1024, 512, 1);
  gemm_mfma_sig_pool<1, 0><<<dim3(8, 4), 256, 0, stream>>>(W2L, b2L, xl1b, xl2, 512, 256, 0);
  lstm_mfma<<<256, 512, 0, stream>>>(xl2, P, Whh3, Wih3, b3, Wout, bout, out);
}